// Round 5
// baseline (454.483 us; speedup 1.0000x reference)
//
#include <hip/hip_runtime.h>
#include <math.h>

#define NB 16
#define NN 24
#define FF 128
#define CC 27
#define MAXN 24      /* physically <= 23 neighbors possible (image spacing L > 2r) */
#define NCAND (NN*NN*CC)   /* 15552 candidate pairs per batch */

// ---- static device scratch (d_ws unused). Only the sigma handoff crosses blocks;
// counters are zero at load and reset by the last-finishing batch block each call.
// All atomics RELAXED agent-scope sc ops (R1/R3 lessons: agent ACQUIRE = whole-L2
// inv, RELEASE = whole-L2 writeback -> device-wide storms). Padded 128-B lines.
__device__ float g_sigma[4];
__device__ __align__(128) int g_sigdone[32];     // sigma blocks done (0..3)
__device__ __align__(128) int g_batchdone[32];   // finished batch blocks (0..NB)

__device__ __forceinline__ float softplusf(float x){ return fmaxf(x,0.f) + log1pf(expf(-fabsf(x))); }
__device__ __forceinline__ float sigmoidf(float x){ return 1.f/(1.f+expf(-x)); }
__device__ __forceinline__ void st_agent(float* p, float v){
  __hip_atomic_store(p, v, __ATOMIC_RELAXED, __HIP_MEMORY_SCOPE_AGENT);
}
__device__ __forceinline__ float ld_agent(const float* p){
  return __hip_atomic_load(p, __ATOMIC_RELAXED, __HIP_MEMORY_SCOPE_AGENT);
}

// Fixed-trip banded Gaussian dot: 20 fully-unrolled terms covering the +-9*step band.
// Terms outside the true band have gauss < 2e-18 -> invisible in fp32 sums.
__device__ __forceinline__ void band_dot(float dist, const float* __restrict__ Wf2,
                                         const float* __restrict__ Ws2, int f,
                                         float& ge, float& se)
{
  const float step  = 6.0f/127.0f;
  const float coeff = -0.5f/(step*step);
  int kmin = (int)ceilf(dist/step - 9.0f);
  kmin = kmin < 0 ? 0 : (kmin > 108 ? 108 : kmin);
  float g = 0.f, s = 0.f;
  #pragma unroll
  for (int t = 0; t < 20; t++) {
    int k = kmin + t;
    float dd = dist - step*(float)k;
    float a  = expf(coeff*dd*dd);
    g += a * Wf2[k*FF+f];
    s += a * Ws2[k*FF+f];
  }
  ge = g; se = s;
}

// ======= single kernel: 16 one-block-per-batch blocks + 3 sigma blocks =======
// 19 blocks x 1024 threads. No cross-block sync except the end-of-kernel sigma
// poll (sigma publishes ~5us in; batch blocks poll it after ~12us of work).
__global__ void __launch_bounds__(1024, 4)
k_fused(const float* __restrict__ pos, const float* __restrict__ cell,
        const float* __restrict__ emb,
        const float* __restrict__ conv_Wf, const float* __restrict__ conv_bf,
        const float* __restrict__ conv_Ws, const float* __restrict__ conv_bs,
        const float* __restrict__ fc_W,  const float* __restrict__ fc_b,
        const float* __restrict__ W_out, const float* __restrict__ b_out,
        const int* __restrict__ z, float* __restrict__ out)
{
  const int tid = threadIdx.x;

  // LDS (shared by both branches; total ~49 KB)
  __shared__ float s_ft[NN*FF];        // running feat (residual state), 12 KB
  __shared__ float s_pj[NN*2*FF];      // {gi,si} then {gj,sj} of current layer, 24 KB
  __shared__ float s_part2[4][FF];     // k-split partials (sigma + FC tail)
  __shared__ float s_hh[FF], s_tmp[FF], s_red[FF];
  __shared__ float s_u[FF], s_v[FF];   // sigma power iteration
  __shared__ float s_pos[NN*3];
  __shared__ float s_cell[9];
  __shared__ float s_rb;
  __shared__ int   s_cnt[NN];
  __shared__ int   s_nbrj[NN*MAXN];    // local j (0..23)
  __shared__ float s_nbrd[NN*MAXN];
  __shared__ float s_nbrw[NN*MAXN];

  if (blockIdx.x >= NB) {
    // ---- spectral-norm power iteration (5 iters, eps=1e-12) -- verbatim R4
    // math on 512 active threads; upper 512 idle through uniform barriers.
    const int m = blockIdx.x - NB;
    const int q = tid >> 7, f = tid & 127;
    const float* W = fc_W + m*FF*FF;
    if (tid < FF) s_u[tid] = 0.08838834764831845f;      // 1/sqrt(128)
    __syncthreads();
    for (int it = 0; it < 5; it++) {
      if (tid < 512) { float p = 0.f;                   // v = W u (k-split)
        #pragma unroll
        for (int k = q*32; k < q*32+32; k++) p += W[f*FF+k]*s_u[k];
        s_part2[q][f] = p; }
      __syncthreads();
      if (tid < FF) { float s = s_part2[0][f]+s_part2[1][f]+s_part2[2][f]+s_part2[3][f];
                      s_v[f] = s; s_red[f] = s*s; }
      __syncthreads();
      for (int st=64; st>0; st>>=1){ if (tid<st) s_red[tid]+=s_red[tid+st]; __syncthreads(); }
      float nv = sqrtf(s_red[0]) + 1e-12f;
      __syncthreads();
      if (tid < FF) s_v[f] /= nv;
      __syncthreads();
      if (tid < 512) { float p = 0.f;                   // u = W^T v (r-split)
        #pragma unroll
        for (int r = q*32; r < q*32+32; r++) p += W[r*FF+f]*s_v[r];
        s_part2[q][f] = p; }
      __syncthreads();
      if (tid < FF) { float s = s_part2[0][f]+s_part2[1][f]+s_part2[2][f]+s_part2[3][f];
                      s_u[f] = s; s_red[f] = s*s; }
      __syncthreads();
      for (int st=64; st>0; st>>=1){ if (tid<st) s_red[tid]+=s_red[tid+st]; __syncthreads(); }
      float nu = sqrtf(s_red[0]) + 1e-12f;
      __syncthreads();
      if (tid < FF) s_u[f] /= nu;
      __syncthreads();
    }
    if (tid < 512) { float p = 0.f;                     // sigma = v . (W u)
      #pragma unroll
      for (int k = q*32; k < q*32+32; k++) p += W[f*FF+k]*s_u[k];
      s_part2[q][f] = p; }
    __syncthreads();
    if (tid < FF) s_red[f] = s_v[f]*(s_part2[0][f]+s_part2[1][f]+s_part2[2][f]+s_part2[3][f]);
    __syncthreads();
    for (int st=64; st>0; st>>=1){ if (tid<st) s_red[tid]+=s_red[tid+st]; __syncthreads(); }
    if (tid == 0) {
      st_agent(&g_sigma[m], s_red[0]);
      asm volatile("s_waitcnt vmcnt(0)" ::: "memory");  // value at LLC before flag
      __hip_atomic_fetch_add(&g_sigdone[0], 1, __ATOMIC_RELAXED, __HIP_MEMORY_SCOPE_AGENT);
    }
    return;
  }

  // ---------------- batch block: whole pipeline for 24 atoms ----------------
  const int b = blockIdx.x;

  // ---- inputs + feat0 ----
  if (tid < 9)    s_cell[tid] = cell[b*9 + tid];
  if (tid < NN)   s_cnt[tid] = 0;
  if (tid < NN*3) s_pos[tid] = pos[b*NN*3 + tid];
  #pragma unroll
  for (int it = 0; it < 3; ++it) {
    int idx = tid + it*1024;              // = i*FF + f
    int i = idx >> 7;
    int zi = z[b*NN + i]; if (zi < 1) zi = 1; if (zi > 100) zi = 100;
    s_ft[idx] = tanhf(emb[(zi-1)*FF + (idx & 127)]);
  }
  __syncthreads();
  if (tid == 0) {
    const float* c = s_cell;
    float cx = c[4]*c[8] - c[5]*c[7];
    float cy = c[5]*c[6] - c[3]*c[8];
    float cz = c[3]*c[7] - c[4]*c[6];
    float vol = c[0]*cx + c[1]*cy + c[2]*cz;
    s_rb = cbrtf(fabsf(vol)/(float)NN);               // RADIUS_RATE = 1
  }
  __syncthreads();

  // ---- neighbor search: all 24x24x27 candidates, LDS lists ----
  {
    const float rb = s_rb, rb2 = rb*rb;
    const float PI = 3.14159265358979323846f;
    #pragma unroll
    for (int it = 0; it < 16; ++it) {
      int cand = tid + it*1024;
      if (cand < NCAND) {
        int i  = cand / (NN*CC);
        int rem = cand - i*(NN*CC);
        int j  = rem / CC;
        int c  = rem - j*CC;
        float gx = (float)(c/9) - 1.0f;
        float gy = (float)((c/3)%3) - 1.0f;
        float gz = (float)(c%3) - 1.0f;
        float ox = gx*s_cell[0] + gy*s_cell[3] + gz*s_cell[6];
        float oy = gx*s_cell[1] + gy*s_cell[4] + gz*s_cell[7];
        float oz = gx*s_cell[2] + gy*s_cell[5] + gz*s_cell[8];
        float dx = s_pos[i*3+0] - (s_pos[j*3+0] + ox);
        float dy = s_pos[i*3+1] - (s_pos[j*3+1] + oy);
        float dz = s_pos[i*3+2] - (s_pos[j*3+2] + oz);
        float d2 = dx*dx + dy*dy + dz*dz;
        if (d2 <= rb2 && d2 > 1e-4f) {
          float dist = sqrtf(fmaxf(d2, 1e-4f));
          float w = cosf(dist*PI/rb) + 1.0f;
          int slot = atomicAdd(&s_cnt[i], 1);          // LDS-local
          if (slot < MAXN) {
            s_nbrj[i*MAXN+slot] = j;
            s_nbrd[i*MAXN+slot] = dist;
            s_nbrw[i*MAXN+slot] = w;
          }
        }
      }
    }
  }
  __syncthreads();

  float pregi[3], presi[3];               // own gi/si, 3 (atom,f) items per thread

  // proj pass: 6144 dots (24 atoms x {f,s} x 128 cols), 6 per thread.
  // rowoff 0 -> "i"-side rows (gi/si); rowoff FF*FF -> "j"-side rows (gj/sj).
  #define PROJ_PASS(WfL, WsL, rowoff)                                     \
  { _Pragma("unroll")                                                     \
    for (int it2 = 0; it2 < 6; ++it2) {                                   \
      int idx = tid + it2*1024;                                           \
      int i = idx >> 8, h = (idx >> 7) & 1, f = idx & 127;                \
      const float* W = ((h==0) ? (WfL) : (WsL)) + (rowoff);               \
      float s = 0.f;                                                      \
      _Pragma("unroll 16")                                                \
      for (int k = 0; k < FF; ++k) s += s_ft[i*FF+k]*W[k*FF+f];           \
      s_pj[(i*2+h)*FF+f] = s;                                             \
    } }

  #define READ_OWN()                                                      \
  { _Pragma("unroll")                                                     \
    for (int it2 = 0; it2 < 3; ++it2) {                                   \
      int idx = tid + it2*1024;                                           \
      int i = idx >> 7, f = idx & 127;                                    \
      pregi[it2] = s_pj[(i*2+0)*FF+f];                                    \
      presi[it2] = s_pj[(i*2+1)*FF+f];                                    \
    } }

  // ---- layer-0 projections ----
  PROJ_PASS(conv_Wf, conv_Ws, 0);
  __syncthreads();
  READ_OWN();
  __syncthreads();
  PROJ_PASS(conv_Wf, conv_Ws, FF*FF);
  __syncthreads();

  #define EDGE_TERM(e, acc)                                               \
  { int j = s_nbrj[i*MAXN+(e)];                                           \
    float dist = s_nbrd[i*MAXN+(e)];                                      \
    float w    = s_nbrw[i*MAXN+(e)];                                      \
    float gj = s_pj[(j*2+0)*FF+f];                                        \
    float sj = s_pj[(j*2+1)*FF+f];                                        \
    float ge, se; band_dot(dist, Wf2, Ws2, f, ge, se);                    \
    acc += sigmoidf(gi + gj + ge + bff) * softplusf(si + sj + se + bsf) * w; }

  for (int l = 0; l < 3; ++l) {
    const float* Wf2 = conv_Wf + l*3*FF*FF + 2*FF*FF;
    const float* Ws2 = conv_Ws + l*3*FF*FF + 2*FF*FF;
    // ---- edge phase: thread owns all edges of its 3 (i,f) items.
    // m0..m3 by e&3 in ascending e == R4's 4-quarter split, bit-identical.
    #pragma unroll
    for (int it2 = 0; it2 < 3; ++it2) {
      int idx = tid + it2*1024;
      int i = idx >> 7, f = idx & 127;
      const float gi = pregi[it2], si = presi[it2];
      const float bff = conv_bf[l*FF+f], bsf = conv_bs[l*FF+f];
      int n = s_cnt[i]; if (n > MAXN) n = MAXN;
      float m0=0.f, m1=0.f, m2=0.f, m3=0.f;
      for (int e = 0; e < n; e += 4) {
        EDGE_TERM(e, m0);
        if (e+1 < n) EDGE_TERM(e+1, m1);
        if (e+2 < n) EDGE_TERM(e+2, m2);
        if (e+3 < n) EDGE_TERM(e+3, m3);
      }
      s_ft[idx] = softplusf(s_ft[idx] + m0 + m1 + m2 + m3);  // own elem only
    }
    __syncthreads();                       // pj reads + ft writes complete
    if (l < 2) {
      const float* Wfn = conv_Wf + (l+1)*3*FF*FF;
      const float* Wsn = conv_Ws + (l+1)*3*FF*FF;
      PROJ_PASS(Wfn, Wsn, 0);
      __syncthreads();
      READ_OWN();
      __syncthreads();
      PROJ_PASS(Wfn, Wsn, FF*FF);
      __syncthreads();
    }
  }

  // ---------- FC tail (per batch block; only sigma crosses blocks) ----------
  if (tid == 0) {
    int guard = 0;
    while (__hip_atomic_load(&g_sigdone[0], __ATOMIC_RELAXED, __HIP_MEMORY_SCOPE_AGENT) < 3) {
      __builtin_amdgcn_s_sleep(4);
      if (++guard > (1<<18)) break;   // fail visibly instead of hanging
    }
  }
  __syncthreads();
  if (tid < FF) {
    float s0 = 0.f;
    for (int a = 0; a < NN; ++a) s0 += s_ft[a*FF+tid];
    s_hh[tid] = s0/(float)NN;
  }
  __syncthreads();
  for (int l = 0; l < 3; ++l) {
    if (tid < 512) {
      const int q = tid >> 7, f = tid & 127;
      float p = 0.f;
      #pragma unroll
      for (int k = q*32; k < q*32+32; ++k) p += s_hh[k]*fc_W[l*FF*FF + k*FF + f];
      s_part2[q][f] = p;
    }
    __syncthreads();
    if (tid < FF) {
      float s = s_part2[0][tid]+s_part2[1][tid]+s_part2[2][tid]+s_part2[3][tid];
      s_tmp[tid] = softplusf(s/ld_agent(&g_sigma[l]) + fc_b[l*FF+tid]);
    }
    __syncthreads();
    if (tid < FF) s_hh[tid] = s_tmp[tid];
    __syncthreads();
  }
  if (tid < FF) s_red[tid] = s_hh[tid]*W_out[tid];
  __syncthreads();
  if (tid < 64) {
    float t = s_red[tid] + s_red[tid+64];
    #pragma unroll
    for (int off = 32; off > 0; off >>= 1) t += __shfl_xor(t, off);
    if (tid == 0) {
      out[b] = t + b_out[0];
      int d = __hip_atomic_fetch_add(&g_batchdone[0], 1, __ATOMIC_RELAXED,
                                     __HIP_MEMORY_SCOPE_AGENT);
      if (d == NB-1) {                     // last batch block: reset for replay
        __hip_atomic_store(&g_batchdone[0], 0, __ATOMIC_RELAXED, __HIP_MEMORY_SCOPE_AGENT);
        __hip_atomic_store(&g_sigdone[0],   0, __ATOMIC_RELAXED, __HIP_MEMORY_SCOPE_AGENT);
      }
    }
  }
}

extern "C" void kernel_launch(void* const* d_in, const int* in_sizes, int n_in,
                              void* d_out, int out_size, void* d_ws, size_t ws_size,
                              hipStream_t stream) {
  const float* pos     = (const float*)d_in[0];
  const float* cell    = (const float*)d_in[1];
  const float* emb     = (const float*)d_in[2];
  const float* conv_Wf = (const float*)d_in[3];
  const float* conv_bf = (const float*)d_in[4];
  const float* conv_Ws = (const float*)d_in[5];
  const float* conv_bs = (const float*)d_in[6];
  const float* fc_W    = (const float*)d_in[7];
  const float* fc_b    = (const float*)d_in[8];
  const float* W_out   = (const float*)d_in[9];
  const float* b_out   = (const float*)d_in[10];
  const int*   z       = (const int*)d_in[11];
  // d_in[12] = batch (unused); d_ws unused. All tensors fp32 (validated R3-R14).

  k_fused<<<NB+3, 1024, 0, stream>>>(pos, cell, emb, conv_Wf, conv_bf,
                                     conv_Ws, conv_bs, fc_W, fc_b,
                                     W_out, b_out, z, (float*)d_out);
}

// Round 6
// 169.470 us; speedup vs baseline: 2.6818x; 2.6818x over previous
//
#include <hip/hip_runtime.h>
#include <math.h>

#define NB 16
#define NN 24
#define NA 384       /* atoms total */
#define FF 128
#define CC 27
#define MAXNBR 32    /* physically <= 23 possible (image spacing L > 2r) */
#define BPB 12       /* blocks per batch (2 atoms per block) */
#define NT 20        /* gauss band terms */

// ---- static device scratch (d_ws unused). Counters zero at load, reset by the
// finisher blocks each call. Each counter owns a 128-B line (R3 lesson: packed
// counters saturate an LLC slice). ALL atomics RELAXED (R1/R3 lessons: agent
// ACQUIRE = whole-L2 inv, RELEASE = whole-L2 writeback -> device-wide storms).
// Ordering is carried by s_waitcnt vmcnt(0) before each counter bump: sc stores
// are physically complete at the LLC (agent coherence point) before the bump.
__device__ float g_sigma[4];
__device__ float g_projA[NA*4*FF];  // P0, then P2
__device__ float g_projB[NA*4*FF];  // P1
__device__ float g_feat [NA*FF];    // final feats (agent-scope)
__device__ __align__(128) int g_ctr[4*NB][32];   // [phase*NB+batch][0]
__device__ __align__(128) int g_sigdone[32];     // sigma blocks done (0..3)
__device__ __align__(128) int g_batchdone[32];   // finished batches (0..NB)

__device__ __forceinline__ float softplusf(float x){ return fmaxf(x,0.f) + log1pf(expf(-fabsf(x))); }
__device__ __forceinline__ float sigmoidf(float x){ return 1.f/(1.f+expf(-x)); }
__device__ __forceinline__ void st_agent(float* p, float v){
  __hip_atomic_store(p, v, __ATOMIC_RELAXED, __HIP_MEMORY_SCOPE_AGENT);
}
__device__ __forceinline__ float ld_agent(const float* p){
  return __hip_atomic_load(p, __ATOMIC_RELAXED, __HIP_MEMORY_SCOPE_AGENT);
}

// Banded Gaussian dot with PRECOMPUTED gauss table (R6): the 20 exp values
// depend only on dist -- not on f (128x) nor layer (3x). R4/R5 recomputed each
// expf 384 times; now they're computed once per edge into LDS. The fmac chain
// g += a*W keeps the exact order/values of the old band_dot -> bit-identical.
__device__ __forceinline__ void band_dot2(const float* __restrict__ ga, int kmin,
                                          const float* __restrict__ Wf2,
                                          const float* __restrict__ Ws2, int f,
                                          float& ge, float& se)
{
  float g = 0.f, s = 0.f;
  #pragma unroll
  for (int t = 0; t < NT; t++) {
    float a = ga[t];
    int k = kmin + t;
    g += a * Wf2[k*FF+f];
    s += a * Ws2[k*FF+f];
  }
  ge = g; se = s;
}

// per-quarter GEMV: quarter q computes one of {gi,gj,si,sj} columns
__device__ __forceinline__ float gemv_q(const float* __restrict__ Wf,
                                        const float* __restrict__ Ws,
                                        const float* s_ft, int q, int f)
{
  const float* W = (q==0) ? Wf : (q==1) ? (Wf + FF*FF) : (q==2) ? Ws : (Ws + FF*FF);
  float s = 0.f;
  #pragma unroll 16
  for (int k = 0; k < FF; k++) s += s_ft[k]*W[k*FF+f];
  return s;
}

// publish own stores at LLC, then bump the per-batch arrival counter (RELAXED).
__device__ __forceinline__ void publish(int* ctr)
{
  asm volatile("s_waitcnt vmcnt(0)" ::: "memory");   // own agent stores at LLC
  __syncthreads();                                    // whole block drained
  if (threadIdx.x == 0)
    __hip_atomic_fetch_add(ctr, 1, __ATOMIC_RELAXED, __HIP_MEMORY_SCOPE_AGENT);
}

// spin (tid 0 only, bounded) with RELAXED polls on a private 128-B line.
// s_sleep(2) ~= 128 cyc; 12 pollers/line == R4's proven per-line poll rate
// at half the detection quantization.
__device__ __forceinline__ void wait_ge(int* ctr, int target)
{
  if (threadIdx.x == 0) {
    int guard = 0;
    while (__hip_atomic_load(ctr, __ATOMIC_RELAXED, __HIP_MEMORY_SCOPE_AGENT) < target) {
      __builtin_amdgcn_s_sleep(2);
      if (++guard > (1<<19)) break;   // fail visibly (absmax) instead of hanging
    }
  }
  __syncthreads();
}

// ====== single fused kernel: 3 sigma blocks + 192 atom-pair blocks ======
// 195 blocks x 512 thr, launch_bounds(512,4) -> all co-resident (>=4 slots/CU).
// 2 atoms per block: halves barrier participants (24->12) and block count vs R4
// while keeping per-CU compute ~16us (R5's 1-block-per-batch hit the 165us
// serialization floor: total VALU work is ~3100 CU*us, invariant across R4/R5).
__global__ void __launch_bounds__(512, 4)
k_fused(const float* __restrict__ pos, const float* __restrict__ cell,
        const float* __restrict__ emb,
        const float* __restrict__ conv_Wf, const float* __restrict__ conv_bf,
        const float* __restrict__ conv_Ws, const float* __restrict__ conv_bs,
        const float* __restrict__ fc_W,  const float* __restrict__ fc_b,
        const float* __restrict__ W_out, const float* __restrict__ b_out,
        const int* __restrict__ z, float* __restrict__ out)
{
  const int tid = threadIdx.x;
  const int q = tid >> 7, f = tid & 127;

  if (blockIdx.x < 3) {
    // ---- spectral-norm power iteration (5 iters, eps=1e-12) -- verbatim R4 ----
    const int m = blockIdx.x;
    const float* W = fc_W + m*FF*FF;
    __shared__ float s_u[FF], s_v[FF], s_red2[FF];
    __shared__ float s_part2[4][FF];
    if (tid < FF) s_u[tid] = 0.08838834764831845f;      // 1/sqrt(128)
    __syncthreads();
    for (int it = 0; it < 5; it++) {
      { float p = 0.f;                                  // v = W u (k-split)
        #pragma unroll
        for (int k = q*32; k < q*32+32; k++) p += W[f*FF+k]*s_u[k];
        s_part2[q][f] = p; }
      __syncthreads();
      if (tid < FF) { float s = s_part2[0][f]+s_part2[1][f]+s_part2[2][f]+s_part2[3][f];
                      s_v[f] = s; s_red2[f] = s*s; }
      __syncthreads();
      for (int st=64; st>0; st>>=1){ if (tid<st) s_red2[tid]+=s_red2[tid+st]; __syncthreads(); }
      float nv = sqrtf(s_red2[0]) + 1e-12f;
      __syncthreads();
      if (tid < FF) s_v[f] /= nv;
      __syncthreads();
      { float p = 0.f;                                  // u = W^T v (r-split)
        #pragma unroll
        for (int r = q*32; r < q*32+32; r++) p += W[r*FF+f]*s_v[r];
        s_part2[q][f] = p; }
      __syncthreads();
      if (tid < FF) { float s = s_part2[0][f]+s_part2[1][f]+s_part2[2][f]+s_part2[3][f];
                      s_u[f] = s; s_red2[f] = s*s; }
      __syncthreads();
      for (int st=64; st>0; st>>=1){ if (tid<st) s_red2[tid]+=s_red2[tid+st]; __syncthreads(); }
      float nu = sqrtf(s_red2[0]) + 1e-12f;
      __syncthreads();
      if (tid < FF) s_u[f] /= nu;
      __syncthreads();
    }
    { float p = 0.f;                                    // sigma = v . (W u)
      #pragma unroll
      for (int k = q*32; k < q*32+32; k++) p += W[f*FF+k]*s_u[k];
      s_part2[q][f] = p; }
    __syncthreads();
    if (tid < FF) s_red2[f] = s_v[f]*(s_part2[0][f]+s_part2[1][f]+s_part2[2][f]+s_part2[3][f]);
    __syncthreads();
    for (int st=64; st>0; st>>=1){ if (tid<st) s_red2[tid]+=s_red2[tid+st]; __syncthreads(); }
    if (tid == 0) {
      st_agent(&g_sigma[m], s_red2[0]);
      asm volatile("s_waitcnt vmcnt(0)" ::: "memory");
      __hip_atomic_fetch_add(&g_sigdone[0], 1, __ATOMIC_RELAXED, __HIP_MEMORY_SCOPE_AGENT);
    }
    return;
  }

  // ---------------- atom-pair block: atoms i0, i0+1 of batch b ----------------
  const int p_  = (int)blockIdx.x - 3;
  const int i0  = 2*p_;
  const int b   = i0 / NN;

  __shared__ float s_ft[2][FF];        // running feats (residual state)
  __shared__ float s_cell[9];
  __shared__ float s_rb;
  __shared__ int   s_cnt[2];
  __shared__ int   s_nj[2][MAXNBR];    // neighbor lists in LDS
  __shared__ float s_nd[2][MAXNBR];
  __shared__ float s_nw[2][MAXNBR];
  __shared__ float s_ga[2][MAXNBR][NT];// per-edge gauss tables (R6)
  __shared__ int   s_km[2][MAXNBR];    // per-edge kmin
  __shared__ float s_p[2][4][FF];      // own {gi,gj,si,sj} projections
  __shared__ float sm[2][4][FF];
  __shared__ int   s_last;
  __shared__ float s_hh[FF], s_tmp[FF], s_red[FF];   // FC tail (finisher only)

  // ---- feat0 + cell ----
  if (tid < 2*FF) {
    int a = tid >> 7, ff = tid & 127;
    int zi = z[i0 + a]; if (zi < 1) zi = 1; if (zi > 100) zi = 100;
    s_ft[a][ff] = tanhf(emb[(zi-1)*FF+ff]);
  }
  if (tid >= 256 && tid < 265) s_cell[tid-256] = cell[b*9 + tid - 256];
  if (tid == 500) { s_cnt[0] = 0; s_cnt[1] = 0; }
  __syncthreads();
  if (tid == 0) {
    const float* c = s_cell;
    float cx = c[4]*c[8] - c[5]*c[7];
    float cy = c[5]*c[6] - c[3]*c[8];
    float cz = c[3]*c[7] - c[4]*c[6];
    float vol = c[0]*cx + c[1]*cy + c[2]*cz;
    s_rb = cbrtf(fabsf(vol)/(float)NN);               // RADIUS_RATE = 1
  }
  __syncthreads();

  // ---- neighbor search (R4 loop, run once per owned atom) ----
  {
    const float rb = s_rb, rb2 = rb*rb;
    const float PI = 3.14159265358979323846f;
    for (int a = 0; a < 2; ++a) {
      const int i = i0 + a;
      const float pix = pos[i*3+0], piy = pos[i*3+1], piz = pos[i*3+2];
      for (int cand = tid; cand < NN*CC; cand += 512) {
        int j = cand / CC, c = cand - j*CC;
        float gx = (float)(c/9) - 1.0f;
        float gy = (float)((c/3)%3) - 1.0f;
        float gz = (float)(c%3) - 1.0f;
        float ox = gx*s_cell[0] + gy*s_cell[3] + gz*s_cell[6];
        float oy = gx*s_cell[1] + gy*s_cell[4] + gz*s_cell[7];
        float oz = gx*s_cell[2] + gy*s_cell[5] + gz*s_cell[8];
        int jg = b*NN + j;
        float dx = pix - (pos[jg*3+0] + ox);
        float dy = piy - (pos[jg*3+1] + oy);
        float dz = piz - (pos[jg*3+2] + oz);
        float d2 = dx*dx + dy*dy + dz*dz;
        if (d2 <= rb2 && d2 > 1e-4f) {
          float dist = sqrtf(fmaxf(d2, 1e-4f));
          float w = cosf(dist*PI/rb) + 1.0f;
          int slot = atomicAdd(&s_cnt[a], 1);           // LDS-local
          if (slot < MAXNBR) { s_nj[a][slot] = jg; s_nd[a][slot] = dist; s_nw[a][slot] = w; }
        }
      }
    }
  }
  __syncthreads();

  // ---- per-edge gauss tables: the expf(coeff*dd*dd) expression is verbatim
  // the old band_dot -> identical bits; each value computed ONCE (was 384x).
  for (int idx = tid; idx < 2*MAXNBR*NT; idx += 512) {
    int a = idx / (MAXNBR*NT);
    int r = idx - a*(MAXNBR*NT);
    int e = r / NT, t = r - e*NT;
    int n = s_cnt[a]; if (n > MAXNBR) n = MAXNBR;
    if (e < n) {
      float dist = s_nd[a][e];
      const float step  = 6.0f/127.0f;
      const float coeff = -0.5f/(step*step);
      int kmin = (int)ceilf(dist/step - 9.0f);
      kmin = kmin < 0 ? 0 : (kmin > 108 ? 108 : kmin);
      if (t == 0) s_km[a][e] = kmin;
      int k = kmin + t;
      float dd = dist - step*(float)k;
      s_ga[a][e][t] = expf(coeff*dd*dd);
    }
  }
  __syncthreads();

  // ---- P0 ----
  #pragma unroll
  for (int a = 0; a < 2; ++a) {
    float s0 = gemv_q(conv_Wf, conv_Ws, s_ft[a], q, f);
    s_p[a][q][f] = s0;
    st_agent(&g_projA[((i0+a)*4+q)*FF+f], s0);
  }
  publish(&g_ctr[0*NB+b][0]);
  wait_ge(&g_ctr[0*NB+b][0], BPB);

  // ---- 3 conv layers: edges (quarter-split per atom, bit-exact R4 order)
  //      + fused next-layer projections ----
  for (int l = 0; l < 3; ++l) {
    const float* projSrc = (l==1) ? g_projB : g_projA;
    const float* Wf2 = conv_Wf + l*3*FF*FF + 2*FF*FF;
    const float* Ws2 = conv_Ws + l*3*FF*FF + 2*FF*FF;
    const float bff = conv_bf[l*FF+f];
    const float bsf = conv_bs[l*FF+f];
    #pragma unroll
    for (int a = 0; a < 2; ++a) {
      const float gi = s_p[a][0][f], si = s_p[a][2][f];
      int n = s_cnt[a]; if (n > MAXNBR) n = MAXNBR;
      float msg = 0.f;
      for (int e = q; e < n; e += 4) {          // e == q mod 4: R4's split
        int   jg   = s_nj[a][e];
        float w    = s_nw[a][e];
        float gj = ld_agent(&projSrc[(jg*4+1)*FF+f]);   // LLC-direct
        float sj = ld_agent(&projSrc[(jg*4+3)*FF+f]);
        float ge, se;
        band_dot2(&s_ga[a][e][0], s_km[a][e], Wf2, Ws2, f, ge, se);
        msg += sigmoidf(gi + gj + ge + bff) * softplusf(si + sj + se + bsf) * w;
      }
      sm[a][q][f] = msg;
    }
    __syncthreads();
    if (tid < 2*FF) {
      int a = tid >> 7, ff = tid & 127;
      s_ft[a][ff] = softplusf(s_ft[a][ff] + sm[a][0][ff] + sm[a][1][ff]
                                          + sm[a][2][ff] + sm[a][3][ff]);
    }
    __syncthreads();
    if (l < 2) {
      const float* WfN = conv_Wf + (l+1)*3*FF*FF;
      const float* WsN = conv_Ws + (l+1)*3*FF*FF;
      float* projDst = (l==0) ? g_projB : g_projA;  // P2 overwrites P0: safe,
      #pragma unroll                                 // P0 readers passed ctr[1]
      for (int a = 0; a < 2; ++a) {
        float s1 = gemv_q(WfN, WsN, s_ft[a], q, f);
        s_p[a][q][f] = s1;
        st_agent(&projDst[((i0+a)*4+q)*FF+f], s1);
      }
      publish(&g_ctr[(l+1)*NB+b][0]);
      wait_ge(&g_ctr[(l+1)*NB+b][0], BPB);
    }
  }

  // ---- final feats + batch arrival ----
  if (tid < 2*FF) {
    int a = tid >> 7, ff = tid & 127;
    st_agent(&g_feat[(i0+a)*FF+ff], s_ft[a][ff]);
  }
  asm volatile("s_waitcnt vmcnt(0)" ::: "memory");
  __syncthreads();
  if (tid == 0)
    s_last = __hip_atomic_fetch_add(&g_ctr[3*NB+b][0], 1, __ATOMIC_RELAXED,
                                    __HIP_MEMORY_SCOPE_AGENT);
  __syncthreads();
  if (s_last != BPB-1) return;                 // not the last block of this batch

  // ---------- unique last block of batch b: mean + FC chain + head ----------
  if (tid == 0) {                              // sigma must be published
    int guard = 0;
    while (__hip_atomic_load(&g_sigdone[0], __ATOMIC_RELAXED, __HIP_MEMORY_SCOPE_AGENT) < 3) {
      __builtin_amdgcn_s_sleep(2);
      if (++guard > (1<<19)) break;
    }
  }
  __syncthreads();
  if (tid < FF) {
    float s0 = 0.f;
    for (int a = 0; a < NN; a++) s0 += ld_agent(&g_feat[(b*NN+a)*FF+tid]);
    s_hh[tid] = s0/(float)NN;
  }
  __syncthreads();
  for (int l = 0; l < 3; l++) {
    { float p = 0.f;
      #pragma unroll
      for (int k = q*32; k < q*32+32; k++) p += s_hh[k]*fc_W[l*FF*FF + k*FF + f];
      sm[0][q][f] = p; }
    __syncthreads();
    if (tid < FF) {
      float s = sm[0][0][tid]+sm[0][1][tid]+sm[0][2][tid]+sm[0][3][tid];
      s_tmp[tid] = softplusf(s/ld_agent(&g_sigma[l]) + fc_b[l*FF+tid]);
    }
    __syncthreads();
    if (tid < FF) s_hh[tid] = s_tmp[tid];
    __syncthreads();
  }
  if (tid < FF) s_red[tid] = s_hh[tid]*W_out[tid];
  __syncthreads();
  if (tid < 64) {
    float t = s_red[tid] + s_red[tid+64];
    #pragma unroll
    for (int off = 32; off > 0; off >>= 1) t += __shfl_xor(t, off);
    if (tid == 0) {
      out[b] = t + b_out[0];
      // reset all per-batch counters for the next graph replay
      __hip_atomic_store(&g_ctr[0*NB+b][0], 0, __ATOMIC_RELAXED, __HIP_MEMORY_SCOPE_AGENT);
      __hip_atomic_store(&g_ctr[1*NB+b][0], 0, __ATOMIC_RELAXED, __HIP_MEMORY_SCOPE_AGENT);
      __hip_atomic_store(&g_ctr[2*NB+b][0], 0, __ATOMIC_RELAXED, __HIP_MEMORY_SCOPE_AGENT);
      __hip_atomic_store(&g_ctr[3*NB+b][0], 0, __ATOMIC_RELAXED, __HIP_MEMORY_SCOPE_AGENT);
      int d = __hip_atomic_fetch_add(&g_batchdone[0], 1, __ATOMIC_RELAXED,
                                     __HIP_MEMORY_SCOPE_AGENT);
      if (d == NB-1) {                         // globally last finisher
        __hip_atomic_store(&g_batchdone[0], 0, __ATOMIC_RELAXED, __HIP_MEMORY_SCOPE_AGENT);
        __hip_atomic_store(&g_sigdone[0],   0, __ATOMIC_RELAXED, __HIP_MEMORY_SCOPE_AGENT);
      }
    }
  }
}

extern "C" void kernel_launch(void* const* d_in, const int* in_sizes, int n_in,
                              void* d_out, int out_size, void* d_ws, size_t ws_size,
                              hipStream_t stream) {
  const float* pos     = (const float*)d_in[0];
  const float* cell    = (const float*)d_in[1];
  const float* emb     = (const float*)d_in[2];
  const float* conv_Wf = (const float*)d_in[3];
  const float* conv_bf = (const float*)d_in[4];
  const float* conv_Ws = (const float*)d_in[5];
  const float* conv_bs = (const float*)d_in[6];
  const float* fc_W    = (const float*)d_in[7];
  const float* fc_b    = (const float*)d_in[8];
  const float* W_out   = (const float*)d_in[9];
  const float* b_out   = (const float*)d_in[10];
  const int*   z       = (const int*)d_in[11];
  // d_in[12] = batch (unused); d_ws unused. All tensors fp32 (validated R3-R14).

  k_fused<<<3 + NA/2, 512, 0, stream>>>(pos, cell, emb, conv_Wf, conv_bf,
                                        conv_Ws, conv_bs, fc_W, fc_b,
                                        W_out, b_out, z, (float*)d_out);
}

// Round 7
// 135.785 us; speedup vs baseline: 3.3471x; 1.2481x over previous
//
#include <hip/hip_runtime.h>
#include <math.h>

#define NB 16
#define NN 24
#define NA 384       /* atoms total */
#define FF 128
#define CC 27
#define MAXNBR 32    /* list capacity; physically <= 23 (image spacing L > 2r) */
#define MAXE 24      /* preact/gauss array size; >= physical max 23 */
#define NT 20        /* gauss band terms */

// ---- static device scratch (d_ws unused). Counters zero at load, reset by the
// finisher blocks each call. Each counter owns a 128-B line (R3 lesson: packed
// counters saturate an LLC slice). ALL atomics RELAXED (R1/R3 lessons: agent
// ACQUIRE = whole-L2 inv, RELEASE = whole-L2 writeback -> device-wide storms).
// Ordering is carried by s_waitcnt vmcnt(0) before each counter bump: sc stores
// are physically complete at the LLC (agent coherence point) before the bump.
__device__ float g_sigma[4];
__device__ float g_projA[NA*4*FF];  // P0, then P2
__device__ float g_projB[NA*4*FF];  // P1
__device__ float g_feat [NA*FF];    // final feats (agent-scope)
__device__ __align__(128) int g_ctr[4*NB][32];   // [phase*NB+batch][0]
__device__ __align__(128) int g_sigdone[32];     // sigma blocks done (0..3)
__device__ __align__(128) int g_batchdone[32];   // finished batches (0..NB)

__device__ __forceinline__ float softplusf(float x){ return fmaxf(x,0.f) + log1pf(expf(-fabsf(x))); }
__device__ __forceinline__ float sigmoidf(float x){ return 1.f/(1.f+expf(-x)); }
__device__ __forceinline__ void st_agent(float* p, float v){
  __hip_atomic_store(p, v, __ATOMIC_RELAXED, __HIP_MEMORY_SCOPE_AGENT);
}
__device__ __forceinline__ float ld_agent(const float* p){
  return __hip_atomic_load(p, __ATOMIC_RELAXED, __HIP_MEMORY_SCOPE_AGENT);
}

// Banded Gaussian dot from PRECOMPUTED gauss table (R6-validated, bit-exact):
// the 20 exp values depend only on dist, computed once per edge in the prologue.
__device__ __forceinline__ void band_dot2(const float* __restrict__ ga, int kmin,
                                          const float* __restrict__ Wf2,
                                          const float* __restrict__ Ws2, int f,
                                          float& ge, float& se)
{
  float g = 0.f, s = 0.f;
  #pragma unroll
  for (int t = 0; t < NT; t++) {
    float a = ga[t];
    int k = kmin + t;
    g += a * Wf2[k*FF+f];
    s += a * Ws2[k*FF+f];
  }
  ge = g; se = s;
}

// per-quarter GEMV: quarter q computes one of {gi,gj,si,sj} columns
__device__ __forceinline__ float gemv_q(const float* __restrict__ Wf,
                                        const float* __restrict__ Ws,
                                        const float* s_ft, int q, int f)
{
  const float* W = (q==0) ? Wf : (q==1) ? (Wf + FF*FF) : (q==2) ? Ws : (Ws + FF*FF);
  float s = 0.f;
  #pragma unroll 16
  for (int k = 0; k < FF; k++) s += s_ft[k]*W[k*FF+f];
  return s;
}

// publish own stores at LLC, then bump the per-batch arrival counter (RELAXED).
__device__ __forceinline__ void publish(int* ctr)
{
  asm volatile("s_waitcnt vmcnt(0)" ::: "memory");   // own agent stores at LLC
  __syncthreads();                                    // whole block drained
  if (threadIdx.x == 0)
    __hip_atomic_fetch_add(ctr, 1, __ATOMIC_RELAXED, __HIP_MEMORY_SCOPE_AGENT);
}

// spin (tid 0 only, bounded) with RELAXED polls on a private 128-B line.
__device__ __forceinline__ void wait_ge(int* ctr, int target)
{
  if (threadIdx.x == 0) {
    int guard = 0;
    while (__hip_atomic_load(ctr, __ATOMIC_RELAXED, __HIP_MEMORY_SCOPE_AGENT) < target) {
      __builtin_amdgcn_s_sleep(4);
      if (++guard > (1<<18)) break;   // fail visibly (absmax) instead of hanging
    }
  }
  __syncthreads();
}

// ============ single fused kernel: 3 sigma blocks + 384 atom blocks ============
// R7 structure: R4's 1-atom-per-block layout (best measured) + R6's gauss
// precompute + NEW preact overlap: the layer-l band_dot outputs ge/se[e][f]
// depend only on dist + layer weights -- NOT on neighbors' projections -- so
// they're computed into LDS BETWEEN publish(l) and wait(l). The barrier wait is
// hidden under ~2-3us of real work; the post-wait combine is featherweight.
__global__ void __launch_bounds__(512, 4)
k_fused(const float* __restrict__ pos, const float* __restrict__ cell,
        const float* __restrict__ emb,
        const float* __restrict__ conv_Wf, const float* __restrict__ conv_bf,
        const float* __restrict__ conv_Ws, const float* __restrict__ conv_bs,
        const float* __restrict__ fc_W,  const float* __restrict__ fc_b,
        const float* __restrict__ W_out, const float* __restrict__ b_out,
        const int* __restrict__ z, float* __restrict__ out)
{
  const int tid = threadIdx.x;
  const int q = tid >> 7, f = tid & 127;

  // shared arrays (atom branch; sigma branch reuses sm/s_hh/s_tmp/s_red)
  __shared__ float s_ft[FF];           // running feat (residual state)
  __shared__ float s_cell[9];
  __shared__ float s_rb;
  __shared__ int   s_cnt;
  __shared__ int   s_nj[MAXNBR];       // neighbor list in LDS
  __shared__ float s_nd[MAXNBR];
  __shared__ float s_nw[MAXNBR];
  __shared__ float s_ga[MAXE][NT];     // per-edge gauss tables (R6)
  __shared__ int   s_km[MAXE];         // per-edge kmin
  __shared__ float s_ge[MAXE][FF];     // preact: band_dot ge outputs (R7)
  __shared__ float s_se[MAXE][FF];     // preact: band_dot se outputs (R7)
  __shared__ float s_p[4][FF];         // own {gi,gj,si,sj} projections
  __shared__ float sm[4][FF];          // msg quarters / GEMV partials
  __shared__ int   s_last;
  __shared__ float s_hh[FF], s_tmp[FF], s_red[FF];

  if (blockIdx.x < 3) {
    // ---- spectral-norm power iteration (5 iters, eps=1e-12) -- verbatim R4,
    // with LDS reuse: s_part2->sm, s_u->s_hh, s_v->s_tmp, s_red2->s_red.
    const int m = blockIdx.x;
    const float* W = fc_W + m*FF*FF;
    if (tid < FF) s_hh[tid] = 0.08838834764831845f;     // u = 1/sqrt(128)
    __syncthreads();
    for (int it = 0; it < 5; it++) {
      { float p = 0.f;                                  // v = W u (k-split)
        #pragma unroll
        for (int k = q*32; k < q*32+32; k++) p += W[f*FF+k]*s_hh[k];
        sm[q][f] = p; }
      __syncthreads();
      if (tid < FF) { float s = sm[0][f]+sm[1][f]+sm[2][f]+sm[3][f];
                      s_tmp[f] = s; s_red[f] = s*s; }
      __syncthreads();
      for (int st=64; st>0; st>>=1){ if (tid<st) s_red[tid]+=s_red[tid+st]; __syncthreads(); }
      float nv = sqrtf(s_red[0]) + 1e-12f;
      __syncthreads();
      if (tid < FF) s_tmp[f] /= nv;
      __syncthreads();
      { float p = 0.f;                                  // u = W^T v (r-split)
        #pragma unroll
        for (int r = q*32; r < q*32+32; r++) p += W[r*FF+f]*s_tmp[r];
        sm[q][f] = p; }
      __syncthreads();
      if (tid < FF) { float s = sm[0][f]+sm[1][f]+sm[2][f]+sm[3][f];
                      s_hh[f] = s; s_red[f] = s*s; }
      __syncthreads();
      for (int st=64; st>0; st>>=1){ if (tid<st) s_red[tid]+=s_red[tid+st]; __syncthreads(); }
      float nu = sqrtf(s_red[0]) + 1e-12f;
      __syncthreads();
      if (tid < FF) s_hh[f] /= nu;
      __syncthreads();
    }
    { float p = 0.f;                                    // sigma = v . (W u)
      #pragma unroll
      for (int k = q*32; k < q*32+32; k++) p += W[f*FF+k]*s_hh[k];
      sm[q][f] = p; }
    __syncthreads();
    if (tid < FF) s_red[f] = s_tmp[f]*(sm[0][f]+sm[1][f]+sm[2][f]+sm[3][f]);
    __syncthreads();
    for (int st=64; st>0; st>>=1){ if (tid<st) s_red[tid]+=s_red[tid+st]; __syncthreads(); }
    if (tid == 0) {
      st_agent(&g_sigma[m], s_red[0]);
      asm volatile("s_waitcnt vmcnt(0)" ::: "memory");
      __hip_atomic_fetch_add(&g_sigdone[0], 1, __ATOMIC_RELAXED, __HIP_MEMORY_SCOPE_AGENT);
    }
    return;
  }

  // ---------------- atom block: whole pipeline for one atom ----------------
  const int i = (int)blockIdx.x - 3;
  const int b = i / NN;

  // ---- feat0 + cell ----
  if (tid < FF) {
    int zi = z[i]; if (zi < 1) zi = 1; if (zi > 100) zi = 100;
    s_ft[tid] = tanhf(emb[(zi-1)*FF+tid]);
  }
  if (tid >= 256 && tid < 265) s_cell[tid-256] = cell[b*9 + tid - 256];
  if (tid == 500) s_cnt = 0;
  __syncthreads();
  if (tid == 0) {
    const float* c = s_cell;
    float cx = c[4]*c[8] - c[5]*c[7];
    float cy = c[5]*c[6] - c[3]*c[8];
    float cz = c[3]*c[7] - c[4]*c[6];
    float vol = c[0]*cx + c[1]*cy + c[2]*cz;
    s_rb = cbrtf(fabsf(vol)/(float)NN);               // RADIUS_RATE = 1
  }
  __syncthreads();
  // ---- neighbor search (LDS lists) ----
  {
    const float rb = s_rb, rb2 = rb*rb;
    const float pix = pos[i*3+0], piy = pos[i*3+1], piz = pos[i*3+2];
    const float PI = 3.14159265358979323846f;
    for (int cand = tid; cand < NN*CC; cand += 512) {
      int j = cand / CC, c = cand - j*CC;
      float gx = (float)(c/9) - 1.0f;
      float gy = (float)((c/3)%3) - 1.0f;
      float gz = (float)(c%3) - 1.0f;
      float ox = gx*s_cell[0] + gy*s_cell[3] + gz*s_cell[6];
      float oy = gx*s_cell[1] + gy*s_cell[4] + gz*s_cell[7];
      float oz = gx*s_cell[2] + gy*s_cell[5] + gz*s_cell[8];
      int jg = b*NN + j;
      float dx = pix - (pos[jg*3+0] + ox);
      float dy = piy - (pos[jg*3+1] + oy);
      float dz = piz - (pos[jg*3+2] + oz);
      float d2 = dx*dx + dy*dy + dz*dz;
      if (d2 <= rb2 && d2 > 1e-4f) {
        float dist = sqrtf(fmaxf(d2, 1e-4f));
        float w = cosf(dist*PI/rb) + 1.0f;
        int slot = atomicAdd(&s_cnt, 1);              // block-local
        if (slot < MAXNBR) { s_nj[slot] = jg; s_nd[slot] = dist; s_nw[slot] = w; }
      }
    }
  }
  __syncthreads();
  const int n0 = (s_cnt > MAXNBR) ? MAXNBR : s_cnt;
  const int n  = (n0 > MAXE) ? MAXE : n0;              // physically n0 <= 23

  // ---- per-edge gauss tables (expf bits identical to R4's band_dot; R6) ----
  for (int idx = tid; idx < n*NT; idx += 512) {
    int e = idx / NT, t = idx - e*NT;
    float dist = s_nd[e];
    const float step  = 6.0f/127.0f;
    const float coeff = -0.5f/(step*step);
    int kmin = (int)ceilf(dist/step - 9.0f);
    kmin = kmin < 0 ? 0 : (kmin > 108 ? 108 : kmin);
    if (t == 0) s_km[e] = kmin;
    int k = kmin + t;
    float dd = dist - step*(float)k;
    s_ga[e][t] = expf(coeff*dd*dd);
  }
  __syncthreads();

  // ---- P0 ----
  { float s0 = gemv_q(conv_Wf, conv_Ws, s_ft, q, f);
    s_p[q][f] = s0;
    st_agent(&g_projA[(i*4+q)*FF+f], s0); }
  publish(&g_ctr[0*NB+b][0]);

  // ---- 3 conv layers: preact (hides barrier) -> wait -> light combine ----
  for (int l = 0; l < 3; ++l) {
    const float* projSrc = (l==1) ? g_projB : g_projA;
    const float* Wf2 = conv_Wf + l*3*FF*FF + 2*FF*FF;
    const float* Ws2 = conv_Ws + l*3*FF*FF + 2*FF*FF;
    // preact: all (e,f) band_dot outputs into LDS. No dependence on other
    // blocks -> runs while the per-batch barrier fills.
    for (int idx = tid; idx < n*FF; idx += 512) {
      int e = idx >> 7, ff = idx & 127;
      float ge, se;
      band_dot2(&s_ga[e][0], s_km[e], Wf2, Ws2, ff, ge, se);
      s_ge[e][ff] = ge; s_se[e][ff] = se;
    }
    __syncthreads();
    wait_ge(&g_ctr[l*NB+b][0], NN);
    // light combine: 2 LLC loads + ~12 VALU per edge. FP order identical to
    // R4: ((gi+gj)+ge)+bff with ge/se substituted from LDS (same bits).
    {
      const float gi = s_p[0][f], si = s_p[2][f];
      const float bff = conv_bf[l*FF+f], bsf = conv_bs[l*FF+f];
      float msg = 0.f;
      for (int e = q; e < n; e += 4) {          // e == q mod 4: R4's split
        int   jg = s_nj[e];
        float w  = s_nw[e];
        float gj = ld_agent(&projSrc[(jg*4+1)*FF+f]);   // LLC-direct
        float sj = ld_agent(&projSrc[(jg*4+3)*FF+f]);
        msg += sigmoidf(gi + gj + s_ge[e][f] + bff)
             * softplusf(si + sj + s_se[e][f] + bsf) * w;
      }
      sm[q][f] = msg;
    }
    __syncthreads();
    if (tid < FF) {
      s_ft[tid] = softplusf(s_ft[tid] + sm[0][tid] + sm[1][tid]
                                      + sm[2][tid] + sm[3][tid]);
    }
    __syncthreads();
    if (l < 2) {
      const float* WfN = conv_Wf + (l+1)*3*FF*FF;
      const float* WsN = conv_Ws + (l+1)*3*FF*FF;
      float* projDst = (l==0) ? g_projB : g_projA;  // P2 overwrites P0: safe,
      float s1 = gemv_q(WfN, WsN, s_ft, q, f);      // P0 readers passed ctr[1]
      s_p[q][f] = s1;
      st_agent(&projDst[(i*4+q)*FF+f], s1);
      publish(&g_ctr[(l+1)*NB+b][0]);
    }
  }

  // ---- final feat + batch arrival ----
  if (tid < FF) st_agent(&g_feat[i*FF+tid], s_ft[tid]);
  asm volatile("s_waitcnt vmcnt(0)" ::: "memory");
  __syncthreads();
  if (tid == 0)
    s_last = __hip_atomic_fetch_add(&g_ctr[3*NB+b][0], 1, __ATOMIC_RELAXED,
                                    __HIP_MEMORY_SCOPE_AGENT);
  __syncthreads();
  if (s_last != NN-1) return;                  // not the last block of this batch

  // ---------- unique last block of batch b: mean + FC chain + head ----------
  if (tid == 0) {                              // sigma must be published
    int guard = 0;
    while (__hip_atomic_load(&g_sigdone[0], __ATOMIC_RELAXED, __HIP_MEMORY_SCOPE_AGENT) < 3) {
      __builtin_amdgcn_s_sleep(4);
      if (++guard > (1<<18)) break;
    }
  }
  __syncthreads();
  if (tid < FF) {
    float s0 = 0.f;
    for (int a = 0; a < NN; a++) s0 += ld_agent(&g_feat[(b*NN+a)*FF+tid]);
    s_hh[tid] = s0/(float)NN;
  }
  __syncthreads();
  for (int l = 0; l < 3; l++) {
    { float p = 0.f;
      #pragma unroll
      for (int k = q*32; k < q*32+32; k++) p += s_hh[k]*fc_W[l*FF*FF + k*FF + f];
      sm[q][f] = p; }
    __syncthreads();
    if (tid < FF) {
      float s = sm[0][tid]+sm[1][tid]+sm[2][tid]+sm[3][tid];
      s_tmp[tid] = softplusf(s/ld_agent(&g_sigma[l]) + fc_b[l*FF+tid]);
    }
    __syncthreads();
    if (tid < FF) s_hh[tid] = s_tmp[tid];
    __syncthreads();
  }
  if (tid < FF) s_red[tid] = s_hh[tid]*W_out[tid];
  __syncthreads();
  if (tid < 64) {
    float t = s_red[tid] + s_red[tid+64];
    #pragma unroll
    for (int off = 32; off > 0; off >>= 1) t += __shfl_xor(t, off);
    if (tid == 0) {
      out[b] = t + b_out[0];
      // reset all per-batch counters for the next graph replay
      __hip_atomic_store(&g_ctr[0*NB+b][0], 0, __ATOMIC_RELAXED, __HIP_MEMORY_SCOPE_AGENT);
      __hip_atomic_store(&g_ctr[1*NB+b][0], 0, __ATOMIC_RELAXED, __HIP_MEMORY_SCOPE_AGENT);
      __hip_atomic_store(&g_ctr[2*NB+b][0], 0, __ATOMIC_RELAXED, __HIP_MEMORY_SCOPE_AGENT);
      __hip_atomic_store(&g_ctr[3*NB+b][0], 0, __ATOMIC_RELAXED, __HIP_MEMORY_SCOPE_AGENT);
      int d = __hip_atomic_fetch_add(&g_batchdone[0], 1, __ATOMIC_RELAXED,
                                     __HIP_MEMORY_SCOPE_AGENT);
      if (d == NB-1) {                         // globally last finisher
        __hip_atomic_store(&g_batchdone[0], 0, __ATOMIC_RELAXED, __HIP_MEMORY_SCOPE_AGENT);
        __hip_atomic_store(&g_sigdone[0],   0, __ATOMIC_RELAXED, __HIP_MEMORY_SCOPE_AGENT);
      }
    }
  }
}

extern "C" void kernel_launch(void* const* d_in, const int* in_sizes, int n_in,
                              void* d_out, int out_size, void* d_ws, size_t ws_size,
                              hipStream_t stream) {
  const float* pos     = (const float*)d_in[0];
  const float* cell    = (const float*)d_in[1];
  const float* emb     = (const float*)d_in[2];
  const float* conv_Wf = (const float*)d_in[3];
  const float* conv_bf = (const float*)d_in[4];
  const float* conv_Ws = (const float*)d_in[5];
  const float* conv_bs = (const float*)d_in[6];
  const float* fc_W    = (const float*)d_in[7];
  const float* fc_b    = (const float*)d_in[8];
  const float* W_out   = (const float*)d_in[9];
  const float* b_out   = (const float*)d_in[10];
  const int*   z       = (const int*)d_in[11];
  // d_in[12] = batch (unused); d_ws unused. All tensors fp32 (validated R3-R14).

  k_fused<<<NA+3, 512, 0, stream>>>(pos, cell, emb, conv_Wf, conv_bf,
                                    conv_Ws, conv_bs, fc_W, fc_b,
                                    W_out, b_out, z, (float*)d_out);
}

// Round 8
// 127.579 us; speedup vs baseline: 3.5624x; 1.0643x over previous
//
#include <hip/hip_runtime.h>
#include <math.h>

#define NB 16
#define NN 24
#define NA 384       /* atoms total */
#define FF 128
#define CC 27
#define MAXNBR 32    /* list capacity; physically <= 23 (image spacing L > 2r) */
#define MAXE 24      /* preact/gauss array size; >= physical max 23 */
#define NT 20        /* gauss band terms */

// ---- static device scratch (d_ws unused). Zero at load; finishers reset their
// batch's flags each call -> clean state per graph replay.
// R8: per-atom DATAFLOW FLAGS replace batch-wide counters. flag[i] = phase of
// atom i (1=P0, 2=P1, 3=P2, 4=feat done). Plain st_agent stores -- NO RMW on
// the sync path at all (R3/R4 lessons: RMW serialization + cache-op storms).
// Block i waits only for flags of its n<=23 NEIGHBORS (symmetric relation), so
// batches pipeline atom-by-atom instead of marching in 24-wide lockstep.
// Buffer-reuse safety: readers of P0[i] = N(i); i overwrites P0[i] (with P2)
// only after flags(N(i))>=2, i.e. every reader finished its layer-0 combine.
__device__ float g_sigma[4];
__device__ float g_projA[NA*4*FF];  // P0, then P2
__device__ float g_projB[NA*4*FF];  // P1
__device__ float g_feat [NA*FF];    // final feats (agent-scope)
__device__ __align__(128) int g_flag[NA][32];    // per-atom phase, own 128-B line
__device__ __align__(128) int g_sigdone[32];     // sigma blocks done (0..3)
__device__ __align__(128) int g_batchdone[32];   // finished batches (0..NB)

__device__ __forceinline__ float softplusf(float x){ return fmaxf(x,0.f) + log1pf(expf(-fabsf(x))); }
__device__ __forceinline__ float sigmoidf(float x){ return 1.f/(1.f+expf(-x)); }
__device__ __forceinline__ void st_agent(float* p, float v){
  __hip_atomic_store(p, v, __ATOMIC_RELAXED, __HIP_MEMORY_SCOPE_AGENT);
}
__device__ __forceinline__ float ld_agent(const float* p){
  return __hip_atomic_load(p, __ATOMIC_RELAXED, __HIP_MEMORY_SCOPE_AGENT);
}
__device__ __forceinline__ void st_agent_i(int* p, int v){
  __hip_atomic_store(p, v, __ATOMIC_RELAXED, __HIP_MEMORY_SCOPE_AGENT);
}
__device__ __forceinline__ int ld_agent_i(const int* p){
  return __hip_atomic_load(p, __ATOMIC_RELAXED, __HIP_MEMORY_SCOPE_AGENT);
}

// Banded Gaussian dot from PRECOMPUTED gauss table (R6-validated, bit-exact).
__device__ __forceinline__ void band_dot2(const float* __restrict__ ga, int kmin,
                                          const float* __restrict__ Wf2,
                                          const float* __restrict__ Ws2, int f,
                                          float& ge, float& se)
{
  float g = 0.f, s = 0.f;
  #pragma unroll
  for (int t = 0; t < NT; t++) {
    float a = ga[t];
    int k = kmin + t;
    g += a * Wf2[k*FF+f];
    s += a * Ws2[k*FF+f];
  }
  ge = g; se = s;
}

// per-quarter GEMV: quarter q computes one of {gi,gj,si,sj} columns
__device__ __forceinline__ float gemv_q(const float* __restrict__ Wf,
                                        const float* __restrict__ Ws,
                                        const float* s_ft, int q, int f)
{
  const float* W = (q==0) ? Wf : (q==1) ? (Wf + FF*FF) : (q==2) ? Ws : (Ws + FF*FF);
  float s = 0.f;
  #pragma unroll 16
  for (int k = 0; k < FF; k++) s += s_ft[k]*W[k*FF+f];
  return s;
}

// drain own stores to LLC, block-wide, then set this atom's phase flag.
__device__ __forceinline__ void flag_set(int i, int v)
{
  asm volatile("s_waitcnt vmcnt(0)" ::: "memory");   // own agent stores at LLC
  __syncthreads();                                    // whole block drained
  if (threadIdx.x == 0) st_agent_i(&g_flag[i][0], v);
}

// wave-0 polls neighbor flags (lane e -> neighbor e); satisfied lanes drop out.
__device__ __forceinline__ void wait_nbrs(int n, const int* s_nj, int target)
{
  if (threadIdx.x < 64) {
    int jg = (threadIdx.x < n) ? s_nj[threadIdx.x] : -1;
    bool sat = (jg < 0);
    int guard = 0;
    for (;;) {
      if (!sat) sat = (ld_agent_i(&g_flag[jg][0]) >= target);
      if (__all(sat)) break;
      __builtin_amdgcn_s_sleep(4);
      if (++guard > (1<<18)) break;   // fail visibly (absmax) instead of hanging
    }
  }
  __syncthreads();
}

// ============ single fused kernel: 3 sigma blocks + 384 atom blocks ============
// 387 blocks x 512 thr; 33KB LDS, <=128 VGPR -> >=2 blocks/CU -> all resident
// (512 slots >= 387): dataflow spins cannot deadlock.
__global__ void __launch_bounds__(512, 4)
k_fused(const float* __restrict__ pos, const float* __restrict__ cell,
        const float* __restrict__ emb,
        const float* __restrict__ conv_Wf, const float* __restrict__ conv_bf,
        const float* __restrict__ conv_Ws, const float* __restrict__ conv_bs,
        const float* __restrict__ fc_W,  const float* __restrict__ fc_b,
        const float* __restrict__ W_out, const float* __restrict__ b_out,
        const int* __restrict__ z, float* __restrict__ out)
{
  const int tid = threadIdx.x;
  const int q = tid >> 7, f = tid & 127;

  // shared arrays (atom branch; sigma branch reuses sm/s_hh/s_tmp/s_red)
  __shared__ float s_ft[FF];           // running feat (residual state)
  __shared__ float s_cell[9];
  __shared__ float s_rb;
  __shared__ int   s_cnt;
  __shared__ int   s_nj[MAXNBR];       // neighbor list in LDS (global atom ids)
  __shared__ float s_nd[MAXNBR];
  __shared__ float s_nw[MAXNBR];
  __shared__ float s_ga[MAXE][NT];     // per-edge gauss tables (R6)
  __shared__ int   s_km[MAXE];         // per-edge kmin
  __shared__ float s_ge[MAXE][FF];     // preact: band_dot ge outputs (R7)
  __shared__ float s_se[MAXE][FF];     // preact: band_dot se outputs (R7)
  __shared__ float s_p[4][FF];         // own {gi,gj,si,sj} projections
  __shared__ float sm[4][FF];          // msg quarters / GEMV partials
  __shared__ float s_hh[FF], s_tmp[FF], s_red[FF];

  if (blockIdx.x < 3) {
    // ---- spectral-norm power iteration (5 iters, eps=1e-12) -- verbatim R7 ----
    const int m = blockIdx.x;
    const float* W = fc_W + m*FF*FF;
    if (tid < FF) s_hh[tid] = 0.08838834764831845f;     // u = 1/sqrt(128)
    __syncthreads();
    for (int it = 0; it < 5; it++) {
      { float p = 0.f;                                  // v = W u (k-split)
        #pragma unroll
        for (int k = q*32; k < q*32+32; k++) p += W[f*FF+k]*s_hh[k];
        sm[q][f] = p; }
      __syncthreads();
      if (tid < FF) { float s = sm[0][f]+sm[1][f]+sm[2][f]+sm[3][f];
                      s_tmp[f] = s; s_red[f] = s*s; }
      __syncthreads();
      for (int st=64; st>0; st>>=1){ if (tid<st) s_red[tid]+=s_red[tid+st]; __syncthreads(); }
      float nv = sqrtf(s_red[0]) + 1e-12f;
      __syncthreads();
      if (tid < FF) s_tmp[f] /= nv;
      __syncthreads();
      { float p = 0.f;                                  // u = W^T v (r-split)
        #pragma unroll
        for (int r = q*32; r < q*32+32; r++) p += W[r*FF+f]*s_tmp[r];
        sm[q][f] = p; }
      __syncthreads();
      if (tid < FF) { float s = sm[0][f]+sm[1][f]+sm[2][f]+sm[3][f];
                      s_hh[f] = s; s_red[f] = s*s; }
      __syncthreads();
      for (int st=64; st>0; st>>=1){ if (tid<st) s_red[tid]+=s_red[tid+st]; __syncthreads(); }
      float nu = sqrtf(s_red[0]) + 1e-12f;
      __syncthreads();
      if (tid < FF) s_hh[f] /= nu;
      __syncthreads();
    }
    { float p = 0.f;                                    // sigma = v . (W u)
      #pragma unroll
      for (int k = q*32; k < q*32+32; k++) p += W[f*FF+k]*s_hh[k];
      sm[q][f] = p; }
    __syncthreads();
    if (tid < FF) s_red[f] = s_tmp[f]*(sm[0][f]+sm[1][f]+sm[2][f]+sm[3][f]);
    __syncthreads();
    for (int st=64; st>0; st>>=1){ if (tid<st) s_red[tid]+=s_red[tid+st]; __syncthreads(); }
    if (tid == 0) {
      st_agent(&g_sigma[m], s_red[0]);
      asm volatile("s_waitcnt vmcnt(0)" ::: "memory");
      __hip_atomic_fetch_add(&g_sigdone[0], 1, __ATOMIC_RELAXED, __HIP_MEMORY_SCOPE_AGENT);
    }
    return;
  }

  // ---------------- atom block: whole pipeline for one atom ----------------
  const int i = (int)blockIdx.x - 3;
  const int b = i / NN;

  // ---- feat0 + cell ----
  if (tid < FF) {
    int zi = z[i]; if (zi < 1) zi = 1; if (zi > 100) zi = 100;
    s_ft[tid] = tanhf(emb[(zi-1)*FF+tid]);
  }
  if (tid >= 256 && tid < 265) s_cell[tid-256] = cell[b*9 + tid - 256];
  if (tid == 500) s_cnt = 0;
  __syncthreads();
  if (tid == 0) {
    const float* c = s_cell;
    float cx = c[4]*c[8] - c[5]*c[7];
    float cy = c[5]*c[6] - c[3]*c[8];
    float cz = c[3]*c[7] - c[4]*c[6];
    float vol = c[0]*cx + c[1]*cy + c[2]*cz;
    s_rb = cbrtf(fabsf(vol)/(float)NN);               // RADIUS_RATE = 1
  }
  __syncthreads();
  // ---- neighbor search (LDS lists; same loop/slot mechanism as R4-R7) ----
  {
    const float rb = s_rb, rb2 = rb*rb;
    const float pix = pos[i*3+0], piy = pos[i*3+1], piz = pos[i*3+2];
    const float PI = 3.14159265358979323846f;
    for (int cand = tid; cand < NN*CC; cand += 512) {
      int j = cand / CC, c = cand - j*CC;
      float gx = (float)(c/9) - 1.0f;
      float gy = (float)((c/3)%3) - 1.0f;
      float gz = (float)(c%3) - 1.0f;
      float ox = gx*s_cell[0] + gy*s_cell[3] + gz*s_cell[6];
      float oy = gx*s_cell[1] + gy*s_cell[4] + gz*s_cell[7];
      float oz = gx*s_cell[2] + gy*s_cell[5] + gz*s_cell[8];
      int jg = b*NN + j;
      float dx = pix - (pos[jg*3+0] + ox);
      float dy = piy - (pos[jg*3+1] + oy);
      float dz = piz - (pos[jg*3+2] + oz);
      float d2 = dx*dx + dy*dy + dz*dz;
      if (d2 <= rb2 && d2 > 1e-4f) {
        float dist = sqrtf(fmaxf(d2, 1e-4f));
        float w = cosf(dist*PI/rb) + 1.0f;
        int slot = atomicAdd(&s_cnt, 1);              // block-local
        if (slot < MAXNBR) { s_nj[slot] = jg; s_nd[slot] = dist; s_nw[slot] = w; }
      }
    }
  }
  __syncthreads();
  const int n0 = (s_cnt > MAXNBR) ? MAXNBR : s_cnt;
  const int n  = (n0 > MAXE) ? MAXE : n0;              // physically n0 <= 23

  // ---- per-edge gauss tables (expf bits identical to R4's band_dot; R6) ----
  for (int idx = tid; idx < n*NT; idx += 512) {
    int e = idx / NT, t = idx - e*NT;
    float dist = s_nd[e];
    const float step  = 6.0f/127.0f;
    const float coeff = -0.5f/(step*step);
    int kmin = (int)ceilf(dist/step - 9.0f);
    kmin = kmin < 0 ? 0 : (kmin > 108 ? 108 : kmin);
    if (t == 0) s_km[e] = kmin;
    int k = kmin + t;
    float dd = dist - step*(float)k;
    s_ga[e][t] = expf(coeff*dd*dd);
  }
  __syncthreads();

  // ---- P0 ----
  { float s0 = gemv_q(conv_Wf, conv_Ws, s_ft, q, f);
    s_p[q][f] = s0;
    st_agent(&g_projA[(i*4+q)*FF+f], s0); }
  flag_set(i, 1);

  // ---- 3 conv layers: preact (hides wait) -> wait(neighbors) -> combine ----
  for (int l = 0; l < 3; ++l) {
    const float* projSrc = (l==1) ? g_projB : g_projA;
    const float* Wf2 = conv_Wf + l*3*FF*FF + 2*FF*FF;
    const float* Ws2 = conv_Ws + l*3*FF*FF + 2*FF*FF;
    // preact: independent of other blocks -> runs while neighbor flags fill.
    for (int idx = tid; idx < n*FF; idx += 512) {
      int e = idx >> 7, ff = idx & 127;
      float ge, se;
      band_dot2(&s_ga[e][0], s_km[e], Wf2, Ws2, ff, ge, se);
      s_ge[e][ff] = ge; s_se[e][ff] = se;
    }
    __syncthreads();
    wait_nbrs(n, s_nj, l+1);
    // combine: prefetch all 12 LLC loads back-to-back (one latency exposure),
    // then accumulate in R4's exact order (quarter q, ascending e).
    {
      const float gi = s_p[0][f], si = s_p[2][f];
      const float bff = conv_bf[l*FF+f], bsf = conv_bs[l*FF+f];
      float gjv[6], sjv[6];
      #pragma unroll
      for (int t = 0; t < 6; ++t) {
        int e = q + 4*t;
        int jg = (e < n) ? s_nj[e] : 0;          // masked lanes read atom 0 (discarded)
        gjv[t] = ld_agent(&projSrc[(jg*4+1)*FF+f]);
        sjv[t] = ld_agent(&projSrc[(jg*4+3)*FF+f]);
      }
      float msg = 0.f;
      #pragma unroll
      for (int t = 0; t < 6; ++t) {
        int e = q + 4*t;
        if (e < n)
          msg += sigmoidf(gi + gjv[t] + s_ge[e][f] + bff)
               * softplusf(si + sjv[t] + s_se[e][f] + bsf) * s_nw[e];
      }
      sm[q][f] = msg;
    }
    __syncthreads();
    if (tid < FF) {
      s_ft[tid] = softplusf(s_ft[tid] + sm[0][tid] + sm[1][tid]
                                      + sm[2][tid] + sm[3][tid]);
    }
    __syncthreads();
    if (l < 2) {
      const float* WfN = conv_Wf + (l+1)*3*FF*FF;
      const float* WsN = conv_Ws + (l+1)*3*FF*FF;
      float* projDst = (l==0) ? g_projB : g_projA;  // P2 over P0: safe (header)
      float s1 = gemv_q(WfN, WsN, s_ft, q, f);
      s_p[q][f] = s1;
      st_agent(&projDst[(i*4+q)*FF+f], s1);
      flag_set(i, l+2);
    }
  }

  // ---- final feat ----
  if (tid < FF) st_agent(&g_feat[i*FF+tid], s_ft[tid]);
  flag_set(i, 4);
  if (i != b*NN) return;                       // only the designated finisher stays

  // ---------- designated finisher of batch b: mean + FC chain + head ----------
  // wait all 24 batch flags == 4 (lanes drop out as satisfied)
  if (tid < 64) {
    int jg = (tid < NN) ? (b*NN + tid) : -1;
    bool sat = (jg < 0);
    int guard = 0;
    for (;;) {
      if (!sat) sat = (ld_agent_i(&g_flag[jg][0]) >= 4);
      if (__all(sat)) break;
      __builtin_amdgcn_s_sleep(4);
      if (++guard > (1<<18)) break;
    }
  }
  __syncthreads();
  if (tid < NN) st_agent_i(&g_flag[b*NN+tid][0], 0);   // reset batch flags (replay)
  if (tid == 0) {                              // sigma must be published
    int guard = 0;
    while (__hip_atomic_load(&g_sigdone[0], __ATOMIC_RELAXED, __HIP_MEMORY_SCOPE_AGENT) < 3) {
      __builtin_amdgcn_s_sleep(4);
      if (++guard > (1<<18)) break;
    }
  }
  __syncthreads();
  if (tid < FF) {
    float s0 = 0.f;
    for (int a = 0; a < NN; a++) s0 += ld_agent(&g_feat[(b*NN+a)*FF+tid]);
    s_hh[tid] = s0/(float)NN;
  }
  __syncthreads();
  for (int l = 0; l < 3; l++) {
    { float p = 0.f;
      #pragma unroll
      for (int k = q*32; k < q*32+32; k++) p += s_hh[k]*fc_W[l*FF*FF + k*FF + f];
      sm[q][f] = p; }
    __syncthreads();
    if (tid < FF) {
      float s = sm[0][tid]+sm[1][tid]+sm[2][tid]+sm[3][tid];
      s_tmp[tid] = softplusf(s/ld_agent(&g_sigma[l]) + fc_b[l*FF+tid]);
    }
    __syncthreads();
    if (tid < FF) s_hh[tid] = s_tmp[tid];
    __syncthreads();
  }
  if (tid < FF) s_red[tid] = s_hh[tid]*W_out[tid];
  __syncthreads();
  if (tid < 64) {
    float t = s_red[tid] + s_red[tid+64];
    #pragma unroll
    for (int off = 32; off > 0; off >>= 1) t += __shfl_xor(t, off);
    if (tid == 0) {
      out[b] = t + b_out[0];
      int d = __hip_atomic_fetch_add(&g_batchdone[0], 1, __ATOMIC_RELAXED,
                                     __HIP_MEMORY_SCOPE_AGENT);
      if (d == NB-1) {                         // globally last finisher
        __hip_atomic_store(&g_batchdone[0], 0, __ATOMIC_RELAXED, __HIP_MEMORY_SCOPE_AGENT);
        __hip_atomic_store(&g_sigdone[0],   0, __ATOMIC_RELAXED, __HIP_MEMORY_SCOPE_AGENT);
      }
    }
  }
}

extern "C" void kernel_launch(void* const* d_in, const int* in_sizes, int n_in,
                              void* d_out, int out_size, void* d_ws, size_t ws_size,
                              hipStream_t stream) {
  const float* pos     = (const float*)d_in[0];
  const float* cell    = (const float*)d_in[1];
  const float* emb     = (const float*)d_in[2];
  const float* conv_Wf = (const float*)d_in[3];
  const float* conv_bf = (const float*)d_in[4];
  const float* conv_Ws = (const float*)d_in[5];
  const float* conv_bs = (const float*)d_in[6];
  const float* fc_W    = (const float*)d_in[7];
  const float* fc_b    = (const float*)d_in[8];
  const float* W_out   = (const float*)d_in[9];
  const float* b_out   = (const float*)d_in[10];
  const int*   z       = (const int*)d_in[11];
  // d_in[12] = batch (unused); d_ws unused. All tensors fp32 (validated R3-R14).

  k_fused<<<NA+3, 512, 0, stream>>>(pos, cell, emb, conv_Wf, conv_bf,
                                    conv_Ws, conv_bs, fc_W, fc_b,
                                    W_out, b_out, z, (float*)d_out);
}